// Round 8
// baseline (255.949 us; speedup 1.0000x reference)
//
#include <hip/hip_runtime.h>

#define T_DIM 512
#define B_DIM 4096
#define L_DIM 4
#define LOG2E 1.44269504088896f
#define TWOLOG2E 2.88539008177793f      // 2*log2(e)
#define HALF_LN2 0.346573590279973f     // 1/(2*log2(e)) = ln(2)/2

// DPP move with compile-time ctrl (bound_ctrl=1: OOB lanes read 0).
template <int CTRL>
__device__ __forceinline__ float dpp_mov(float v) {
  int r = __builtin_amdgcn_update_dpp(0, __builtin_bit_cast(int, v), CTRL, 0xf, 0xf, true);
  return __builtin_bit_cast(float, r);
}
template <int CTRL>
__device__ __forceinline__ float qp_add(float v) { return v + dpp_mov<CTRL>(v); }

#define SCHED_FENCE __builtin_amdgcn_sched_barrier(0)

// ---------------- gate-split layer-skewed fused LSTM -------------------------
// R8: TWO INDEPENDENT STREAMS PER WAVE (in-wave ILP).
// 256 blocks x 128 threads = 512 waves, 2 waves/CU. Each wave carries 8
// chains as 2 streams x 4 chains in SEPARATE REGISTERS; cell calls are
// interleaved P0,Q0,P1,Q1,... so stream Q's instructions fill stream P's
// dependency-stall slots (and vice versa) deterministically, inside one
// instruction stream. Rationale: R6 showed 2x redundant issue costs only
// 1.26x wall (stall-filling works); R3-R7 showed 1-wave scheduling cannot
// fill the serial chain's stalls. This is the non-redundant version.
// Half the SIMDs idle by design — we are latency-bound, not machine-bound.
//
// lane = 16*c + 4*l + g: chain c (16-lane row), layer l, gate g.
// Stream P chain = blockIdx*16 + wid*8 + c; stream Q = P + 4. Block covers 16
// consecutive chains -> output stores still fill whole 64B lines (R3 fix).
// Skew: quad (c,l) is at time t = k - l; h_{l-1}(t) arrives via row_shr:4.
//
// Cell is the R4 version (fewest instructions): in the interleaved regime we
// approach issue-bound, so instruction count matters more than chain depth
// (R7's longer-but-shallower cell is reverted).
//
// Layer-0 GEMV: lane loads ONE float x[chain][4l+g]; gate-g's chunk-l dot via
// 3 quad_perm rotations + 4 fmas; chunk-sum via two row_ror DPP butterflies.
// Weights shared by both streams. All off the serial chain, one chunk
// prefetched ahead; sched_barrier(0) after each load block pins the prefetch
// (the scheduler repeatedly sank these loads in R3-R7).
//
// Gates: 1 exp2 + 1 rcp per lane; all four (i,f,g~,o) gathered with 4
// quad_perm reads. Weights pre-scaled by -log2e (i,f,o) / +2log2e (g~);
// cell state tracked scaled (cse = 2log2e*c) so tanh's exp2 consumes it.
__global__ __launch_bounds__(128, 1) void lstm_fused(
    const float* __restrict__ x,      // [T,B,16]
    const float* __restrict__ Wih0,   // [4,16]
    const float* __restrict__ Wrest,  // [3,4]
    const float* __restrict__ Whh,    // [4,4]
    const float* __restrict__ bih, const float* __restrict__ bhh,
    float* __restrict__ out) {
  const int tid = threadIdx.x;
  const int lane = tid & 63;
  const int wid = tid >> 6;               // wave id in block, 0..1
  const int g = lane & 3;
  const int l = (lane >> 2) & 3;
  const int c = (lane >> 4) & 3;
  const int chainP = blockIdx.x * 16 + wid * 8 + c;   // stream Q = chainP + 4
  const bool l0 = (l == 0);

  // gate scale: -log2e for sigmoid gates (i,f,o), +2log2e for tanh (g~).
  auto sg = [](int i) { return (i == 2) ? 2.0f * LOG2E : -LOG2E; };

  // recurrent weights for this lane's (l, g) — shared by both streams
  const float whh  = sg(g) * Whh[l * 4 + g];
  const float wih  = l0 ? 0.f : sg(g) * Wrest[(l - 1) * 4 + g];
  const float base = l0 ? 0.f : sg(g) * (bih[l * 4 + g] + bhh[l * 4 + g]);

  // rotate-dot weights: round r multiplies x[c][4l+((g+r)&3)] (from the quad
  // rotation) by wq_r = sg(g)*Wih0[g][4l+((g+r)&3)].
  float wq0, wq1, wq2, wq3;
  {
    const float s = sg(g);
    wq0 = s * Wih0[g * 16 + 4 * l + ((g + 0) & 3)];
    wq1 = s * Wih0[g * 16 + 4 * l + ((g + 1) & 3)];
    wq2 = s * Wih0[g * 16 + 4 * l + ((g + 2) & 3)];
    wq3 = s * Wih0[g * 16 + 4 * l + ((g + 3) & 3)];
  }
  // layer-0 bias: only l==0 lanes carry it into the l-reduction (added once).
  const float dinit = l0 ? sg(g) * (bih[g] + bhh[g]) : 0.f;
  // gate post-map: sigmoid lanes v = r (identity); tanh lane v = 2log2e*(1-2r).
  const float vm = (g == 2) ? -2.f * TWOLOG2E : 1.f;
  const float va = (g == 2) ? TWOLOG2E : 0.f;

  // x as [T][B*16] floats; stream P reads chainP*16 + 4l + g, Q at +64 floats
  // (folds into the load's immediate offset). Wave reads 512B contiguous per t.
  const float* __restrict__ xp = x + (size_t)chainP * 16 + (size_t)(4 * l + g);
  float* __restrict__ poP = out + chainP;
  float* __restrict__ poQ = poP + 4;

  float hP = 0.f, cseP = 0.f;
  float hQ = 0.f, cseQ = 0.f;
  float AP[8], AQ[8], BP[8], BQ[8];       // constant-indexed only -> VGPRs

#define LOAD8(R, t0, off)                                                   \
  do {                                                                      \
    R[0] = xp[(size_t)((t0) + 0) * 65536 + (off)];                          \
    R[1] = xp[(size_t)((t0) + 1) * 65536 + (off)];                          \
    R[2] = xp[(size_t)((t0) + 2) * 65536 + (off)];                          \
    R[3] = xp[(size_t)((t0) + 3) * 65536 + (off)];                          \
    R[4] = xp[(size_t)((t0) + 4) * 65536 + (off)];                          \
    R[5] = xp[(size_t)((t0) + 5) * 65536 + (off)];                          \
    R[6] = xp[(size_t)((t0) + 6) * 65536 + (off)];                          \
    R[7] = xp[(size_t)((t0) + 7) * 65536 + (off)];                          \
  } while (0)

  // layer-0 gate dot from scalar x: pure VALU, no h dependence.
  // quad_perm sel[i]=(i+r)&3: r=1 -> 0x39, r=2 -> 0x4E, r=3 -> 0x93.
  auto dotD = [&](float xv) -> float {
    float x1 = dpp_mov<0x39>(xv);
    float x2 = dpp_mov<0x4E>(xv);
    float x3 = dpp_mov<0x93>(xv);
    float p = fmaf(xv, wq0, dinit);
    p = fmaf(x1, wq1, p);
    p = fmaf(x2, wq2, p);
    p = fmaf(x3, wq3, p);
    p = qp_add<0x124>(p);                  // row_ror:4
    p = qp_add<0x128>(p);                  // row_ror:8 -> full gate-g dot everywhere
    return p;
  };

  // R4 cell, parameterized by stream state (fully inlined; refs are SROA-safe).
  auto cellv = [&](int k, float D, float& hS, float& cseS, float* __restrict__ poS,
                   bool guard) {
    float hin = dpp_mov<0x114>(hS);          // row_shr:4 -> h_{l-1}(t); 0 for l=0
    float pb = l0 ? D : base;
    float gate = fmaf(whh, hS, fmaf(wih, hin, pb));

    float r = __builtin_amdgcn_rcpf(1.0f + __builtin_amdgcn_exp2f(gate));
    float v = fmaf(vm, r, va);               // lane g: i, f, 2log2e*g~, o

    float i_  = dpp_mov<0x00>(v);            // quad lane0: i
    float f_  = dpp_mov<0x55>(v);            // quad lane1: f
    float tgs = dpp_mov<0xAA>(v);            // quad lane2: 2log2e*g~
    float o_  = dpp_mov<0xFF>(v);            // quad lane3: o
    float cne = fmaf(f_, cseS, i_ * tgs);    // scaled cell state, all lanes
    float tcn = fmaf(-2.0f,
        __builtin_amdgcn_rcpf(1.0f + __builtin_amdgcn_exp2f(cne)), 1.0f);
    float hm = o_ * tcn;                     // valid in ALL lanes

    if (guard) {
      const bool valid = (unsigned)(k - l) < (unsigned)T_DIM;
      cseS = valid ? cne : cseS;
      hS   = valid ? hm : hS;
    } else {
      cseS = cne; hS = hm;
    }
    const int t = k - 3;
    if (l == 3 && g == 0 && (unsigned)t < (unsigned)T_DIM)
      poS[(size_t)t * B_DIM] = hm;
  };

  // Chunk body: 16 off-chain gate dots, then 16 cells interleaved P/Q — the
  // two streams are independent, so Q's ops fill P's chain stalls.
#define CELLS8(RP, RQ, k0, guard)                                           \
  do {                                                                      \
    float DP0 = dotD(RP[0]), DP1 = dotD(RP[1]), DP2 = dotD(RP[2]),          \
          DP3 = dotD(RP[3]), DP4 = dotD(RP[4]), DP5 = dotD(RP[5]),          \
          DP6 = dotD(RP[6]), DP7 = dotD(RP[7]);                             \
    float DQ0 = dotD(RQ[0]), DQ1 = dotD(RQ[1]), DQ2 = dotD(RQ[2]),          \
          DQ3 = dotD(RQ[3]), DQ4 = dotD(RQ[4]), DQ5 = dotD(RQ[5]),          \
          DQ6 = dotD(RQ[6]), DQ7 = dotD(RQ[7]);                             \
    cellv((k0) + 0, DP0, hP, cseP, poP, guard);                             \
    cellv((k0) + 0, DQ0, hQ, cseQ, poQ, guard);                             \
    cellv((k0) + 1, DP1, hP, cseP, poP, guard);                             \
    cellv((k0) + 1, DQ1, hQ, cseQ, poQ, guard);                             \
    cellv((k0) + 2, DP2, hP, cseP, poP, guard);                             \
    cellv((k0) + 2, DQ2, hQ, cseQ, poQ, guard);                             \
    cellv((k0) + 3, DP3, hP, cseP, poP, guard);                             \
    cellv((k0) + 3, DQ3, hQ, cseQ, poQ, guard);                             \
    cellv((k0) + 4, DP4, hP, cseP, poP, guard);                             \
    cellv((k0) + 4, DQ4, hQ, cseQ, poQ, guard);                             \
    cellv((k0) + 5, DP5, hP, cseP, poP, guard);                             \
    cellv((k0) + 5, DQ5, hQ, cseQ, poQ, guard);                             \
    cellv((k0) + 6, DP6, hP, cseP, poP, guard);                             \
    cellv((k0) + 6, DQ6, hQ, cseQ, poQ, guard);                             \
    cellv((k0) + 7, DP7, hP, cseP, poP, guard);                             \
    cellv((k0) + 7, DQ7, hQ, cseQ, poQ, guard);                             \
  } while (0)

  // Software pipeline: issue chunk n+1's loads (both streams), fence so the
  // scheduler cannot sink them, then run chunk n's cells.
  LOAD8(AP, 0, 0); LOAD8(AQ, 0, 64);
  SCHED_FENCE;
  LOAD8(BP, 8, 0); LOAD8(BQ, 8, 64);
  SCHED_FENCE;
  CELLS8(AP, AQ, 0, true);                               // warm-up k=0..7
#pragma unroll 1
  for (int n = 1; n < 63; n += 2) {
    LOAD8(AP, 8 * (n + 1), 0); LOAD8(AQ, 8 * (n + 1), 64);
    SCHED_FENCE;
    CELLS8(BP, BQ, 8 * n, false);
    LOAD8(BP, 8 * (n + 2), 0); LOAD8(BQ, 8 * (n + 2), 64);
    SCHED_FENCE;
    CELLS8(AP, AQ, 8 * (n + 1), false);
  }
  // chunk 63 (k=504..511): B was loaded with t=504 in the last loop iter
  CELLS8(BP, BQ, 504, false);
  // drain (k=512..519): stale-but-finite xv; guard freezes all state, stores
  // are range-checked (t=509..511 emitted here)
  CELLS8(BP, BQ, 512, true);

  // hn, cn: every lane of quad (c,l) holds (h,cse) of its layer at T-1
  if (g == 0) {
    poP[(size_t)T_DIM * B_DIM + (size_t)l * B_DIM] = hP;
    poP[(size_t)T_DIM * B_DIM + (size_t)L_DIM * B_DIM + (size_t)l * B_DIM] =
        cseP * HALF_LN2;
    poQ[(size_t)T_DIM * B_DIM + (size_t)l * B_DIM] = hQ;
    poQ[(size_t)T_DIM * B_DIM + (size_t)L_DIM * B_DIM + (size_t)l * B_DIM] =
        cseQ * HALF_LN2;
  }
#undef LOAD8
#undef CELLS8
}

extern "C" void kernel_launch(void* const* d_in, const int* in_sizes, int n_in,
                              void* d_out, int out_size, void* d_ws, size_t ws_size,
                              hipStream_t stream) {
  const float* x     = (const float*)d_in[0];
  const float* Wih0  = (const float*)d_in[1];
  const float* Wrest = (const float*)d_in[2];
  const float* Whh   = (const float*)d_in[3];
  const float* bih   = (const float*)d_in[4];
  const float* bhh   = (const float*)d_in[5];
  float* out = (float*)d_out;
  lstm_fused<<<B_DIM / 16, 128, 0, stream>>>(x, Wih0, Wrest, Whh, bih, bhh, out);
}